// Round 3
// baseline (146.034 us; speedup 1.0000x reference)
//
#include <hip/hip_runtime.h>
#include <math.h>

#define NB      64
#define NPTS    12288
#define KTOP    10
#define LK      16                // register list length (power of 2)
#define NKP     9
#define CHUNKS  8
#define CHUNK_N (NPTS / CHUNKS)   // 1536
#define T1      256
#define T2      128

struct Pair { float v; int i; };

__device__ __forceinline__ bool better(const Pair& a, const Pair& b) {
    // matches jax.lax.top_k ordering: value descending, index ascending on ties
    return (a.v > b.v) || (a.v == b.v && a.i < b.i);
}

__device__ __forceinline__ void ce(Pair& x, Pair& y) {  // put better at x
    if (better(y, x)) { Pair t = x; x = y; y = t; }
}

// Merge two descending 16-lists -> descending top-16 of the union, in place in A.
// C_i = max(A_i, B_{15-i}) is the top-16 multiset (bitonic top-k theorem) and is
// circularly bitonic, so a 4-stage bitonic network sorts it descending.
// All indices static -> pure VGPR, branch-free.
__device__ __forceinline__ void merge16(Pair (&A)[LK], const Pair (&B)[LK]) {
    Pair C[LK];
    #pragma unroll
    for (int i = 0; i < LK; ++i) {
        Pair a = A[i], b = B[LK - 1 - i];
        C[i] = better(a, b) ? a : b;
    }
    #pragma unroll
    for (int d = LK / 2; d >= 1; d >>= 1) {
        #pragma unroll
        for (int i = 0; i < LK; ++i)
            if ((i & d) == 0) ce(C[i], C[i + d]);
    }
    #pragma unroll
    for (int i = 0; i < LK; ++i) A[i] = C[i];
}

__device__ __forceinline__ void shfl_merge(Pair (&A)[LK], int s) {
    Pair B[LK];
    #pragma unroll
    for (int i = 0; i < LK; ++i) {
        B[i].v = __shfl_xor(A[i].v, s);
        B[i].i = __shfl_xor(A[i].i, s);
    }
    merge16(A, B);
}

// ---------------- Kernel 1: per-chunk top-16 via register bitonic + shfl ----------------
__global__ __launch_bounds__(T1)
void topk_part(const float* __restrict__ seg, Pair* __restrict__ part) {
    const int blk = blockIdx.x;
    const int b = blk >> 3;          // /CHUNKS
    const int chunk = blk & 7;       // %CHUNKS
    const int t = threadIdx.x;
    const int lane = t & 63;
    const int w = t >> 6;

    __shared__ Pair sm[4][LK];

    const float* segb = seg + (size_t)b * NPTS + (size_t)chunk * CHUNK_N;
    const int base = chunk * CHUNK_N;

    // 6 values/thread: one float4 ([0,1024)) + one float2 ([1024,1536))
    float4 a4 = ((const float4*)segb)[t];
    float2 a2 = ((const float2*)(segb + 1024))[t];

    Pair L[LK];
    L[0] = {a4.x, base + 4 * t + 0};
    L[1] = {a4.y, base + 4 * t + 1};
    L[2] = {a4.z, base + 4 * t + 2};
    L[3] = {a4.w, base + 4 * t + 3};
    L[4] = {a2.x, base + 1024 + 2 * t + 0};
    L[5] = {a2.y, base + 1024 + 2 * t + 1};
    #pragma unroll
    for (int i = 6; i < LK; ++i) { L[i].v = -INFINITY; L[i].i = 0x7fffffff; }

    // odd-even transposition sort of the 6 real entries (descending), static indices
    #pragma unroll
    for (int r = 0; r < 6; ++r) {
        if (r & 1) { ce(L[1], L[2]); ce(L[3], L[4]); }
        else       { ce(L[0], L[1]); ce(L[2], L[3]); ce(L[4], L[5]); }
    }

    // intra-wave merge tree: every lane ends with the wave top-16
    shfl_merge(L, 1);  shfl_merge(L, 2);  shfl_merge(L, 4);
    shfl_merge(L, 8);  shfl_merge(L, 16); shfl_merge(L, 32);

    if (lane == 0) {
        #pragma unroll
        for (int j = 0; j < LK; ++j) sm[w][j] = L[j];
    }
    __syncthreads();

    // wave 0 merges the 4 wave lists (2 shfl levels)
    if (t < 64) {
        Pair M[LK];
        #pragma unroll
        for (int j = 0; j < LK; ++j) M[j] = sm[t & 3][j];  // same-addr broadcast, no conflict
        shfl_merge(M, 1); shfl_merge(M, 2);
        if (t == 0) {
            #pragma unroll
            for (int j = 0; j < LK; ++j) part[(size_t)blk * LK + j] = M[j];
        }
    }
}

// ---------------- Kernel 2: merge partials + gather + cluster + Kabsch ----------------
__global__ __launch_bounds__(T2)
void pose_finish(const float* __restrict__ pcld,   // [b, n, 3]
                 const float* __restrict__ kpts,   // [b, n, 8, 3]
                 const float* __restrict__ cpt,    // [b, n, 1, 3]
                 const float* __restrict__ mesh,   // [b, 9, 3]
                 const Pair*  __restrict__ part,   // [b, CHUNKS, 16]
                 float* __restrict__ out)          // R[64,3,3] | t[64,3] | voted[64,9,3]
{
    const int b = blockIdx.x;
    const int t = threadIdx.x;

    __shared__ int   topidx[KTOP];
    __shared__ float cands[NKP][KTOP][3];
    __shared__ float voted[NKP][3];

    // wave 0: lanes load one chunk list each (lane&7), 3 shfl merge levels -> batch top-16
    if (t < 64) {
        Pair M[LK];
        const Pair* src = part + ((size_t)b * CHUNKS + (t & 7)) * LK;
        #pragma unroll
        for (int j = 0; j < LK; ++j) M[j] = src[j];   // 16 independent 8B loads, one vmcnt round
        shfl_merge(M, 1); shfl_merge(M, 2); shfl_merge(M, 4);
        if (t == 0) {
            #pragma unroll
            for (int j = 0; j < KTOP; ++j) topidx[j] = M[j].i;
        }
    }
    __syncthreads();
    // topidx = batch-global top-10 indices, (value-desc, idx-asc) == jax.lax.top_k order.

    // ---- gather 9x10 candidate keypoints ----
    if (t < NKP * KTOP) {
        int j = t / KTOP;   // keypoint channel (0..7 = kpts offsets, 8 = cpt offset)
        int i = t % KTOP;   // candidate rank
        int p = topidx[i];
        size_t base = (size_t)b * NPTS + p;
        float px = pcld[base * 3 + 0], py = pcld[base * 3 + 1], pz = pcld[base * 3 + 2];
        float ox, oy, oz;
        if (j < 8) {
            size_t kb = (base * 8 + j) * 3;
            ox = kpts[kb + 0]; oy = kpts[kb + 1]; oz = kpts[kb + 2];
        } else {
            size_t cb = base * 3;
            ox = cpt[cb + 0]; oy = cpt[cb + 1]; oz = cpt[cb + 2];
        }
        cands[j][i][0] = px + ox;
        cands[j][i][1] = py + oy;
        cands[j][i][2] = pz + oz;
    }
    __syncthreads();

    // ---- sigma-clip clustering per keypoint (fp32, numpy order) ----
    if (t < NKP) {
        float mean[3] = {0.f, 0.f, 0.f};
        for (int i = 0; i < KTOP; ++i)
            for (int c = 0; c < 3; ++c) mean[c] += cands[t][i][c];
        for (int c = 0; c < 3; ++c) mean[c] *= (1.0f / KTOP);
        float var[3] = {0.f, 0.f, 0.f};
        for (int i = 0; i < KTOP; ++i)
            for (int c = 0; c < 3; ++c) { float d = cands[t][i][c] - mean[c]; var[c] += d * d; }
        float sd[3];
        for (int c = 0; c < 3; ++c) sd[c] = sqrtf(var[c] * (1.0f / KTOP));
        float wsum = 0.f, acc[3] = {0.f, 0.f, 0.f};
        for (int i = 0; i < KTOP; ++i) {
            bool in = true;
            for (int c = 0; c < 3; ++c) in = in && (fabsf(cands[t][i][c] - mean[c]) <= sd[c]);
            if (in) {
                wsum += 1.f;
                for (int c = 0; c < 3; ++c) acc[c] += cands[t][i][c];
            }
        }
        float inv = 1.f / (wsum + 1e-6f);
        for (int c = 0; c < 3; ++c) {
            float v = acc[c] * inv;
            voted[t][c] = v;
            out[NB * 9 + NB * 3 + ((size_t)b * NKP + t) * 3 + c] = v;  // kpts_voted at offset 768
        }
    }
    __syncthreads();

    // ---- weighted Kabsch (w = 1), 3x3 SVD via Jacobi on H^T H, double ----
    if (t == 0) {
        const float* mb = mesh + (size_t)b * NKP * 3;
        double A[NKP][3], Bv[NKP][3];
        double cA[3] = {0, 0, 0}, cB[3] = {0, 0, 0};
        for (int n = 0; n < NKP; ++n) {
            for (int c = 0; c < 3; ++c) {
                A[n][c]  = (double)mb[n * 3 + c];
                Bv[n][c] = (double)voted[n][c];
                cA[c] += A[n][c];
                cB[c] += Bv[n][c];
            }
        }
        for (int c = 0; c < 3; ++c) { cA[c] /= NKP; cB[c] /= NKP; }

        double H[3][3] = {{0,0,0},{0,0,0},{0,0,0}};
        for (int n = 0; n < NKP; ++n)
            for (int i = 0; i < 3; ++i)
                for (int j = 0; j < 3; ++j)
                    H[i][j] += (A[n][i] - cA[i]) * (Bv[n][j] - cB[j]);

        double Km[3][3];
        for (int i = 0; i < 3; ++i)
            for (int j = 0; j < 3; ++j) {
                double s = 0;
                for (int l = 0; l < 3; ++l) s += H[l][i] * H[l][j];
                Km[i][j] = s;
            }

        double V[3][3] = {{1,0,0},{0,1,0},{0,0,1}};
        for (int sweep = 0; sweep < 6; ++sweep) {      // 3x3 Jacobi converges quadratically;
            for (int p = 0; p < 2; ++p) {              // post-convergence rotations skip cheaply
                for (int q = p + 1; q < 3; ++q) {
                    double apq = Km[p][q];
                    double app = Km[p][p], aqq = Km[q][q];
                    if (fabs(apq) <= 1e-30 * (fabs(app) + fabs(aqq)) || apq == 0.0) continue;
                    double theta = (aqq - app) / (2.0 * apq);
                    double tj = ((theta >= 0.0) ? 1.0 : -1.0) / (fabs(theta) + sqrt(theta * theta + 1.0));
                    double cj = 1.0 / sqrt(tj * tj + 1.0);
                    double sj = tj * cj;
                    for (int l = 0; l < 3; ++l) {
                        double klp = Km[l][p], klq = Km[l][q];
                        Km[l][p] = cj * klp - sj * klq;
                        Km[l][q] = sj * klp + cj * klq;
                    }
                    for (int l = 0; l < 3; ++l) {
                        double kpl = Km[p][l], kql = Km[q][l];
                        Km[p][l] = cj * kpl - sj * kql;
                        Km[q][l] = sj * kpl + cj * kql;
                    }
                    for (int l = 0; l < 3; ++l) {
                        double vlp = V[l][p], vlq = V[l][q];
                        V[l][p] = cj * vlp - sj * vlq;
                        V[l][q] = sj * vlp + cj * vlq;
                    }
                }
            }
        }

        double eig[3] = {Km[0][0], Km[1][1], Km[2][2]};
        int ord[3] = {0, 1, 2};
        if (eig[ord[0]] < eig[ord[1]]) { int tmp = ord[0]; ord[0] = ord[1]; ord[1] = tmp; }
        if (eig[ord[1]] < eig[ord[2]]) { int tmp = ord[1]; ord[1] = ord[2]; ord[2] = tmp; }
        if (eig[ord[0]] < eig[ord[1]]) { int tmp = ord[0]; ord[0] = ord[1]; ord[1] = tmp; }

        double detH =
            H[0][0] * (H[1][1] * H[2][2] - H[1][2] * H[2][1]) -
            H[0][1] * (H[1][0] * H[2][2] - H[1][2] * H[2][0]) +
            H[0][2] * (H[1][0] * H[2][1] - H[1][1] * H[2][0]);
        double dsign[3] = {1.0, 1.0, (detH < 0.0) ? -1.0 : 1.0};

        double R[3][3] = {{0,0,0},{0,0,0},{0,0,0}};
        for (int k = 0; k < 3; ++k) {
            int c = ord[k];
            double s = sqrt(fmax(eig[c], 0.0));
            double invs = 1.0 / fmax(s, 1e-12);
            double u[3];
            for (int l = 0; l < 3; ++l) {
                double a = 0;
                for (int m = 0; m < 3; ++m) a += H[l][m] * V[m][c];
                u[l] = a * invs;
            }
            for (int r = 0; r < 3; ++r)
                for (int cc = 0; cc < 3; ++cc)
                    R[r][cc] += dsign[k] * V[r][c] * u[cc];
        }

        double tv[3];
        for (int c = 0; c < 3; ++c) {
            double a = 0;
            for (int m = 0; m < 3; ++m) a += R[c][m] * cA[m];
            tv[c] = cB[c] - a;
        }

        for (int r = 0; r < 3; ++r)
            for (int c = 0; c < 3; ++c)
                out[(size_t)b * 9 + r * 3 + c] = (float)R[r][c];         // batch_R
        for (int c = 0; c < 3; ++c)
            out[NB * 9 + (size_t)b * 3 + c] = (float)tv[c];              // batch_t at offset 576
    }
}

extern "C" void kernel_launch(void* const* d_in, const int* in_sizes, int n_in,
                              void* d_out, int out_size, void* d_ws, size_t ws_size,
                              hipStream_t stream) {
    const float* pcld = (const float*)d_in[0];   // [64,12288,3]
    const float* kpts = (const float*)d_in[1];   // [64,12288,8,3]
    const float* cpt  = (const float*)d_in[2];   // [64,12288,1,3]
    const float* seg  = (const float*)d_in[3];   // [64,12288,1]
    const float* mesh = (const float*)d_in[4];   // [64,9,3]
    float* out = (float*)d_out;                  // 576 (R) + 192 (t) + 1728 (voted)
    Pair* part = (Pair*)d_ws;                    // [64][8][16] Pairs = 65536 B

    topk_part<<<NB * CHUNKS, T1, 0, stream>>>(seg, part);
    pose_finish<<<NB, T2, 0, stream>>>(pcld, kpts, cpt, mesh, part, out);
}

// Round 4
// 137.595 us; speedup vs baseline: 1.0613x; 1.0613x over previous
//
#include <hip/hip_runtime.h>
#include <math.h>

#define NB      64
#define NPTS    12288
#define KTOP    10
#define NKP     9
#define T       1024
#define NWAVES  (T / 64)          // 16
#define PERTHD  (NPTS / T)        // 12

struct Pair { float v; int i; };

__device__ __forceinline__ bool better(const Pair& a, const Pair& b) {
    // matches jax.lax.top_k ordering: value descending, index ascending on ties
    return (a.v > b.v) || (a.v == b.v && a.i < b.i);
}

__device__ __forceinline__ void ce(Pair& x, Pair& y) {  // put better at x
    if (better(y, x)) { Pair t = x; x = y; y = t; }
}

// branch-free descending sort, static indices (odd-even transposition)
template <int LEN>
__device__ __forceinline__ void lane_sort_desc(Pair (&L)[LEN]) {
    #pragma unroll
    for (int r = 0; r < LEN; ++r) {
        #pragma unroll
        for (int i = 0; i + 1 < LEN; i += 2) {
            if ((r & 1) == 0) ce(L[i], L[i + 1]);
        }
        #pragma unroll
        for (int i = 1; i + 1 < LEN; i += 2) {
            if ((r & 1) == 1) ce(L[i], L[i + 1]);
        }
    }
}

// Iterative wave-wide top-10 extraction. Each lane holds a DESCENDING list L.
// Pops exactly in (v desc, idx asc) global order == jax.lax.top_k order.
// Requires >= KTOP real values across the wave; exhausted slots are sentinels.
template <int LEN>
__device__ __forceinline__ void wave_topk(Pair (&L)[LEN], Pair (&out)[KTOP]) {
    #pragma unroll
    for (int k = 0; k < KTOP; ++k) {
        Pair w = L[0];
        #pragma unroll
        for (int s = 1; s < 64; s <<= 1) {
            Pair o;
            o.v = __shfl_xor(w.v, s);
            o.i = __shfl_xor(w.i, s);
            if (better(o, w)) w = o;
        }
        out[k] = w;                                   // uniform across wave
        if (L[0].v == w.v && L[0].i == w.i) {         // owning lane pops
            #pragma unroll
            for (int i = 0; i + 1 < LEN; ++i) L[i] = L[i + 1];
            L[LEN - 1].v = -INFINITY; L[LEN - 1].i = 0x7fffffff;
        }
    }
}

__global__ __launch_bounds__(T)
void pose_fused(const float* __restrict__ pcld,   // [b, n, 3]
                const float* __restrict__ kpts,   // [b, n, 8, 3]
                const float* __restrict__ cpt,    // [b, n, 1, 3]
                const float* __restrict__ seg,    // [b, n, 1]
                const float* __restrict__ mesh,   // [b, 9, 3]
                float* __restrict__ out)          // R[64,3,3] | t[64,3] | voted[64,9,3]
{
    const int b = blockIdx.x;
    const int t = threadIdx.x;
    const int lane = t & 63;
    const int w = t >> 6;

    __shared__ Pair  wavetop[NWAVES][KTOP];   // 1280 B
    __shared__ int   topidx[KTOP];
    __shared__ float cands[NKP][KTOP][3];
    __shared__ float voted[NKP][3];

    // ---- Phase A: coalesced load of 12 seg values/thread, lane sort ----
    const float4* segb4 = (const float4*)(seg + (size_t)b * NPTS);  // 3072 float4s
    Pair L[PERTHD];
    #pragma unroll
    for (int j = 0; j < 3; ++j) {
        int f4 = t + j * T;                  // 0..3071
        float4 a = segb4[f4];
        L[4 * j + 0] = {a.x, 4 * f4 + 0};
        L[4 * j + 1] = {a.y, 4 * f4 + 1};
        L[4 * j + 2] = {a.z, 4 * f4 + 2};
        L[4 * j + 3] = {a.w, 4 * f4 + 3};
    }
    lane_sort_desc<PERTHD>(L);

    // ---- Phase B: per-wave top-10 by extraction ----
    Pair wt[KTOP];
    wave_topk<PERTHD>(L, wt);
    if (lane == 0) {
        #pragma unroll
        for (int j = 0; j < KTOP; ++j) wavetop[w][j] = wt[j];
    }
    __syncthreads();

    // ---- Phase C: wave 0 merges the 16 wave lists by extraction ----
    if (w == 0) {
        Pair M[KTOP];
        if (lane < NWAVES) {
            #pragma unroll
            for (int j = 0; j < KTOP; ++j) M[j] = wavetop[lane][j];
        } else {
            #pragma unroll
            for (int j = 0; j < KTOP; ++j) { M[j].v = -INFINITY; M[j].i = 0x7fffffff; }
        }
        Pair top[KTOP];
        wave_topk<KTOP>(M, top);
        if (lane == 0) {
            #pragma unroll
            for (int j = 0; j < KTOP; ++j) topidx[j] = top[j].i;
        }
    }
    __syncthreads();
    // topidx = batch-global top-10 indices, (value-desc, idx-asc) == jax.lax.top_k.

    // ---- Phase D: gather 9x10 candidate keypoints ----
    if (t < NKP * KTOP) {
        int j = t / KTOP;   // keypoint channel (0..7 = kpts offsets, 8 = cpt offset)
        int i = t % KTOP;   // candidate rank
        int p = topidx[i];
        size_t base = (size_t)b * NPTS + p;
        float px = pcld[base * 3 + 0], py = pcld[base * 3 + 1], pz = pcld[base * 3 + 2];
        float ox, oy, oz;
        if (j < 8) {
            size_t kb = (base * 8 + j) * 3;
            ox = kpts[kb + 0]; oy = kpts[kb + 1]; oz = kpts[kb + 2];
        } else {
            size_t cb = base * 3;
            ox = cpt[cb + 0]; oy = cpt[cb + 1]; oz = cpt[cb + 2];
        }
        cands[j][i][0] = px + ox;
        cands[j][i][1] = py + oy;
        cands[j][i][2] = pz + oz;
    }
    __syncthreads();

    // ---- Phase E: sigma-clip clustering per keypoint (fp32, numpy order) ----
    if (t < NKP) {
        float mean[3] = {0.f, 0.f, 0.f};
        for (int i = 0; i < KTOP; ++i)
            for (int c = 0; c < 3; ++c) mean[c] += cands[t][i][c];
        for (int c = 0; c < 3; ++c) mean[c] *= (1.0f / KTOP);
        float var[3] = {0.f, 0.f, 0.f};
        for (int i = 0; i < KTOP; ++i)
            for (int c = 0; c < 3; ++c) { float d = cands[t][i][c] - mean[c]; var[c] += d * d; }
        float sd[3];
        for (int c = 0; c < 3; ++c) sd[c] = sqrtf(var[c] * (1.0f / KTOP));
        float wsum = 0.f, acc[3] = {0.f, 0.f, 0.f};
        for (int i = 0; i < KTOP; ++i) {
            bool in = true;
            for (int c = 0; c < 3; ++c) in = in && (fabsf(cands[t][i][c] - mean[c]) <= sd[c]);
            if (in) {
                wsum += 1.f;
                for (int c = 0; c < 3; ++c) acc[c] += cands[t][i][c];
            }
        }
        float inv = 1.f / (wsum + 1e-6f);
        for (int c = 0; c < 3; ++c) {
            float v = acc[c] * inv;
            voted[t][c] = v;
            out[NB * 9 + NB * 3 + ((size_t)b * NKP + t) * 3 + c] = v;  // kpts_voted at offset 768
        }
    }
    __syncthreads();

    // ---- Phase F: weighted Kabsch (w = 1), 3x3 SVD via Jacobi on H^T H, double ----
    if (t == 0) {
        const float* mb = mesh + (size_t)b * NKP * 3;
        double A[NKP][3], Bv[NKP][3];
        double cA[3] = {0, 0, 0}, cB[3] = {0, 0, 0};
        for (int n = 0; n < NKP; ++n) {
            for (int c = 0; c < 3; ++c) {
                A[n][c]  = (double)mb[n * 3 + c];
                Bv[n][c] = (double)voted[n][c];
                cA[c] += A[n][c];
                cB[c] += Bv[n][c];
            }
        }
        for (int c = 0; c < 3; ++c) { cA[c] /= NKP; cB[c] /= NKP; }

        double H[3][3] = {{0,0,0},{0,0,0},{0,0,0}};
        for (int n = 0; n < NKP; ++n)
            for (int i = 0; i < 3; ++i)
                for (int j = 0; j < 3; ++j)
                    H[i][j] += (A[n][i] - cA[i]) * (Bv[n][j] - cB[j]);

        double Km[3][3];
        for (int i = 0; i < 3; ++i)
            for (int j = 0; j < 3; ++j) {
                double s = 0;
                for (int l = 0; l < 3; ++l) s += H[l][i] * H[l][j];
                Km[i][j] = s;
            }

        double V[3][3] = {{1,0,0},{0,1,0},{0,0,1}};
        for (int sweep = 0; sweep < 6; ++sweep) {
            for (int p = 0; p < 2; ++p) {
                for (int q = p + 1; q < 3; ++q) {
                    double apq = Km[p][q];
                    double app = Km[p][p], aqq = Km[q][q];
                    if (fabs(apq) <= 1e-30 * (fabs(app) + fabs(aqq)) || apq == 0.0) continue;
                    double theta = (aqq - app) / (2.0 * apq);
                    double tj = ((theta >= 0.0) ? 1.0 : -1.0) / (fabs(theta) + sqrt(theta * theta + 1.0));
                    double cj = 1.0 / sqrt(tj * tj + 1.0);
                    double sj = tj * cj;
                    for (int l = 0; l < 3; ++l) {
                        double klp = Km[l][p], klq = Km[l][q];
                        Km[l][p] = cj * klp - sj * klq;
                        Km[l][q] = sj * klp + cj * klq;
                    }
                    for (int l = 0; l < 3; ++l) {
                        double kpl = Km[p][l], kql = Km[q][l];
                        Km[p][l] = cj * kpl - sj * kql;
                        Km[q][l] = sj * kpl + cj * kql;
                    }
                    for (int l = 0; l < 3; ++l) {
                        double vlp = V[l][p], vlq = V[l][q];
                        V[l][p] = cj * vlp - sj * vlq;
                        V[l][q] = sj * vlp + cj * vlq;
                    }
                }
            }
        }

        double eig[3] = {Km[0][0], Km[1][1], Km[2][2]};
        int ord[3] = {0, 1, 2};
        if (eig[ord[0]] < eig[ord[1]]) { int tmp = ord[0]; ord[0] = ord[1]; ord[1] = tmp; }
        if (eig[ord[1]] < eig[ord[2]]) { int tmp = ord[1]; ord[1] = ord[2]; ord[2] = tmp; }
        if (eig[ord[0]] < eig[ord[1]]) { int tmp = ord[0]; ord[0] = ord[1]; ord[1] = tmp; }

        double detH =
            H[0][0] * (H[1][1] * H[2][2] - H[1][2] * H[2][1]) -
            H[0][1] * (H[1][0] * H[2][2] - H[1][2] * H[2][0]) +
            H[0][2] * (H[1][0] * H[2][1] - H[1][1] * H[2][0]);
        double dsign[3] = {1.0, 1.0, (detH < 0.0) ? -1.0 : 1.0};

        double R[3][3] = {{0,0,0},{0,0,0},{0,0,0}};
        for (int k = 0; k < 3; ++k) {
            int c = ord[k];
            double s = sqrt(fmax(eig[c], 0.0));
            double invs = 1.0 / fmax(s, 1e-12);
            double u[3];
            for (int l = 0; l < 3; ++l) {
                double a = 0;
                for (int m = 0; m < 3; ++m) a += H[l][m] * V[m][c];
                u[l] = a * invs;
            }
            for (int r = 0; r < 3; ++r)
                for (int cc = 0; cc < 3; ++cc)
                    R[r][cc] += dsign[k] * V[r][c] * u[cc];
        }

        double tv[3];
        for (int c = 0; c < 3; ++c) {
            double a = 0;
            for (int m = 0; m < 3; ++m) a += R[c][m] * cA[m];
            tv[c] = cB[c] - a;
        }

        for (int r = 0; r < 3; ++r)
            for (int c = 0; c < 3; ++c)
                out[(size_t)b * 9 + r * 3 + c] = (float)R[r][c];         // batch_R
        for (int c = 0; c < 3; ++c)
            out[NB * 9 + (size_t)b * 3 + c] = (float)tv[c];              // batch_t at offset 576
    }
}

extern "C" void kernel_launch(void* const* d_in, const int* in_sizes, int n_in,
                              void* d_out, int out_size, void* d_ws, size_t ws_size,
                              hipStream_t stream) {
    const float* pcld = (const float*)d_in[0];   // [64,12288,3]
    const float* kpts = (const float*)d_in[1];   // [64,12288,8,3]
    const float* cpt  = (const float*)d_in[2];   // [64,12288,1,3]
    const float* seg  = (const float*)d_in[3];   // [64,12288,1]
    const float* mesh = (const float*)d_in[4];   // [64,9,3]
    float* out = (float*)d_out;                  // 576 (R) + 192 (t) + 1728 (voted)

    pose_fused<<<NB, T, 0, stream>>>(pcld, kpts, cpt, seg, mesh, out);
}